// Round 5
// baseline (468.894 us; speedup 1.0000x reference)
//
#include <hip/hip_runtime.h>

#define N_NODES   150000
#define N_EDGES   3000000
#define EMBED_DIM 64
#define SCAN_BLOCK 256
#define N_SCAN_BLOCKS ((N_NODES + SCAN_BLOCK - 1) / SCAN_BLOCK)   // 586
#define N_UNITS   (N_EDGES / 4)                                   // 750000 int4 units
#define NODES_PER_REGION (N_NODES / 8)                            // 18750
#define NSUB 8

typedef unsigned int uint;

// ---- bf16 helpers (RNE pack, shift unpack) ----
__device__ inline uint pack2_bf16(float a, float b) {
    uint ua = __float_as_uint(a);
    uint ub = __float_as_uint(b);
    ua += 0x7fffu + ((ua >> 16) & 1u);
    ub += 0x7fffu + ((ub >> 16) & 1u);
    return (ua >> 16) | (ub & 0xffff0000u);
}
#define FMA2(u, A0, A1)                                        \
    {   float _lo = __uint_as_float((u) << 16);                \
        float _hi = __uint_as_float((u) & 0xffff0000u);        \
        (A0) += w * _lo;  (A1) += w * _hi; }

// ---------- fp32 -> bf16 convert ----------
__global__ void k_to_bf16(const float4* __restrict__ in, uint2* __restrict__ out, int n4) {
    int i = blockIdx.x * blockDim.x + threadIdx.x;
    if (i < n4) {
        float4 v = in[i];
        out[i] = make_uint2(pack2_bf16(v.x, v.y), pack2_bf16(v.z, v.w));
    }
}

// ---------- 8-way sub-histogram + per-edge (sub,rank):  ----------
// deg8 is plane-major: deg8[sub*N + node]. sub = edge_index & 7.
// ranksrc[e] = (sub<<28) | (subrank<<18) | src   (src < 2^18, subrank << 2^10)
__global__ void k_hist_rank(const int4* __restrict__ dst4, const int4* __restrict__ src4,
                            uint* __restrict__ deg8, uint4* __restrict__ ranksrc4) {
    int u = blockIdx.x * blockDim.x + threadIdx.x;
    if (u >= N_UNITS) return;
    int4 d = dst4[u];
    int4 s = src4[u];
    uint base = ((uint)(u << 2)) & 7u;        // 0 or 4
    uint r0 = atomicAdd(&deg8[(base + 0) * N_NODES + d.x], 1u);
    uint r1 = atomicAdd(&deg8[(base + 1) * N_NODES + d.y], 1u);
    uint r2 = atomicAdd(&deg8[(base + 2) * N_NODES + d.z], 1u);
    uint r3 = atomicAdd(&deg8[(base + 3) * N_NODES + d.w], 1u);
    uint4 o;
    o.x = ((base + 0) << 28) | (r0 << 18) | (uint)s.x;
    o.y = ((base + 1) << 28) | (r1 << 18) | (uint)s.y;
    o.z = ((base + 2) << 28) | (r2 << 18) | (uint)s.z;
    o.w = ((base + 3) << 28) | (r3 << 18) | (uint)s.w;
    ranksrc4[u] = o;
}

// ---------- per-node prefix over the 8 sub-counts ----------
// deg8[s][n] (counts) -> exclusive offsets within node n's row; deg[n] = total.
__global__ void k_suboff(uint* __restrict__ deg8, uint* __restrict__ deg) {
    int n = blockIdx.x * blockDim.x + threadIdx.x;
    if (n >= N_NODES) return;
    uint run = 0;
    #pragma unroll
    for (int s = 0; s < NSUB; ++s) {
        uint c = deg8[s * N_NODES + n];
        deg8[s * N_NODES + n] = run;
        run += c;
    }
    deg[n] = run;
}

// ---------- scan stage 1: per-block sums ----------
__global__ void k_blocksum(const uint* __restrict__ deg, int* __restrict__ bsum) {
    __shared__ int s[SCAN_BLOCK];
    int i = blockIdx.x * SCAN_BLOCK + threadIdx.x;
    s[threadIdx.x] = (i < N_NODES) ? (int)deg[i] : 0;
    __syncthreads();
    for (int off = SCAN_BLOCK / 2; off > 0; off >>= 1) {
        if (threadIdx.x < off) s[threadIdx.x] += s[threadIdx.x + off];
        __syncthreads();
    }
    if (threadIdx.x == 0) bsum[blockIdx.x] = s[0];
}

// ---------- scan stage 2: single-block exclusive scan of block sums ----------
__global__ void k_scan_bsums(int* __restrict__ bsum) {
    __shared__ int s[1024];
    int t = threadIdx.x;
    int v = (t < N_SCAN_BLOCKS) ? bsum[t] : 0;
    s[t] = v;
    __syncthreads();
    for (int off = 1; off < 1024; off <<= 1) {
        int add = (t >= off) ? s[t - off] : 0;
        __syncthreads();
        s[t] += add;
        __syncthreads();
    }
    if (t < N_SCAN_BLOCKS) bsum[t] = s[t] - v;
}

// ---------- scan stage 3: final exclusive scan -> rowptr ----------
__global__ void k_scan_final(const uint* __restrict__ deg, const int* __restrict__ bsum,
                             int* __restrict__ rowptr) {
    __shared__ int s[SCAN_BLOCK];
    int i = blockIdx.x * SCAN_BLOCK + threadIdx.x;
    int t = threadIdx.x;
    int v = (i < N_NODES) ? (int)deg[i] : 0;
    s[t] = v;
    __syncthreads();
    for (int off = 1; off < SCAN_BLOCK; off <<= 1) {
        int add = (t >= off) ? s[t - off] : 0;
        __syncthreads();
        s[t] += add;
        __syncthreads();
    }
    if (i < N_NODES) rowptr[i] = s[t] - v + bsum[blockIdx.x];
}

// ---------- XCD-homed, atomic-free CSR scatter ----------
// pos = rowptr[d] + suboff(d,sub) + subrank
__global__ __launch_bounds__(256) void k_scatter_swz(const int4* __restrict__ dst4,
                                                     const uint4* __restrict__ rs4,
                                                     const float* __restrict__ sd,
                                                     const int* __restrict__ rowptr,
                                                     const uint* __restrict__ deg8,
                                                     int2* __restrict__ srcw) {
    const int  grp = blockIdx.x & 7;
    const int  lo  = grp * NODES_PER_REGION;
    const int  bIn = blockIdx.x >> 3;
    const int  nBIn = (int)gridDim.x >> 3;
    const int  stride = nBIn * 256;

    for (int u = bIn * 256 + (int)threadIdx.x; u < N_UNITS; u += stride) {
        int4 d = dst4[u];
        bool m0 = (uint)(d.x - lo) < (uint)NODES_PER_REGION;
        bool m1 = (uint)(d.y - lo) < (uint)NODES_PER_REGION;
        bool m2 = (uint)(d.z - lo) < (uint)NODES_PER_REGION;
        bool m3 = (uint)(d.w - lo) < (uint)NODES_PER_REGION;
        if (m0 | m1 | m2 | m3) {
            uint4 rs = rs4[u];
            if (m0) { uint s = rs.x & 0x3FFFFu, r = (rs.x >> 18) & 0x3FFu, sub = rs.x >> 28;
                      float w = sd[s] * sd[d.x];
                      int pos = rowptr[d.x] + (int)(deg8[sub * N_NODES + d.x] + r);
                      srcw[pos] = make_int2((int)s, __float_as_int(w)); }
            if (m1) { uint s = rs.y & 0x3FFFFu, r = (rs.y >> 18) & 0x3FFu, sub = rs.y >> 28;
                      float w = sd[s] * sd[d.y];
                      int pos = rowptr[d.y] + (int)(deg8[sub * N_NODES + d.y] + r);
                      srcw[pos] = make_int2((int)s, __float_as_int(w)); }
            if (m2) { uint s = rs.z & 0x3FFFFu, r = (rs.z >> 18) & 0x3FFu, sub = rs.z >> 28;
                      float w = sd[s] * sd[d.z];
                      int pos = rowptr[d.z] + (int)(deg8[sub * N_NODES + d.z] + r);
                      srcw[pos] = make_int2((int)s, __float_as_int(w)); }
            if (m3) { uint s = rs.w & 0x3FFFFu, r = (rs.w >> 18) & 0x3FFu, sub = rs.w >> 28;
                      float w = sd[s] * sd[d.w];
                      int pos = rowptr[d.w] + (int)(deg8[sub * N_NODES + d.w] + r);
                      srcw[pos] = make_int2((int)s, __float_as_int(w)); }
        }
    }
}

// ---------- layer: wave-per-node gather over bf16 rows ----------
__global__ __launch_bounds__(256) void k_layer(const uint4* __restrict__ xb,
                                               const int* __restrict__ rowptr,
                                               const int2* __restrict__ srcw,
                                               uint4* __restrict__ aggb) {
    int wid = (blockIdx.x * blockDim.x + threadIdx.x) >> 6;
    if (wid >= N_NODES) return;                 // wave-uniform exit
    int lane = threadIdx.x & 63;
    int ep = lane >> 3;     // edge slot 0..7
    int j  = lane & 7;      // 16B chunk (dims j*8 .. j*8+7)

    int start = rowptr[wid];
    int end   = (wid + 1 < N_NODES) ? rowptr[wid + 1] : N_EDGES;

    float a0 = 0.f, a1 = 0.f, a2 = 0.f, a3 = 0.f;
    float a4 = 0.f, a5 = 0.f, a6 = 0.f, a7 = 0.f;
    for (int base = start; base < end; base += 8) {
        int ee = base + ep;
        if (ee < end) {
            int2 sw = srcw[ee];
            float w = __int_as_float(sw.y);
            uint4 v = xb[(size_t)sw.x * 8 + j];
            FMA2(v.x, a0, a1);
            FMA2(v.y, a2, a3);
            FMA2(v.z, a4, a5);
            FMA2(v.w, a6, a7);
        }
    }
    #pragma unroll
    for (int m = 8; m <= 32; m <<= 1) {
        a0 += __shfl_xor(a0, m, 64);
        a1 += __shfl_xor(a1, m, 64);
        a2 += __shfl_xor(a2, m, 64);
        a3 += __shfl_xor(a3, m, 64);
        a4 += __shfl_xor(a4, m, 64);
        a5 += __shfl_xor(a5, m, 64);
        a6 += __shfl_xor(a6, m, 64);
        a7 += __shfl_xor(a7, m, 64);
    }
    if (ep == 0) {
        uint4 r;
        r.x = pack2_bf16(a0, a1);
        r.y = pack2_bf16(a2, a3);
        r.z = pack2_bf16(a4, a5);
        r.w = pack2_bf16(a6, a7);
        aggb[(size_t)wid * 8 + j] = r;
    }
}

// ---------- final: out = 0.25*(emb + a1 + a2 + a3) ----------
__global__ void k_combine(const float4* __restrict__ emb,
                          const uint2* __restrict__ b1,
                          const uint2* __restrict__ b2,
                          const uint2* __restrict__ b3,
                          float4* __restrict__ out, int n4) {
    int i = blockIdx.x * blockDim.x + threadIdx.x;
    if (i >= n4) return;
    float4 e = emb[i];
    uint2 u1 = b1[i], u2 = b2[i], u3 = b3[i];
    float4 o;
    o.x = e.x + __uint_as_float(u1.x << 16)         + __uint_as_float(u2.x << 16)         + __uint_as_float(u3.x << 16);
    o.y = e.y + __uint_as_float(u1.x & 0xffff0000u) + __uint_as_float(u2.x & 0xffff0000u) + __uint_as_float(u3.x & 0xffff0000u);
    o.z = e.z + __uint_as_float(u1.y << 16)         + __uint_as_float(u2.y << 16)         + __uint_as_float(u3.y << 16);
    o.w = e.w + __uint_as_float(u1.y & 0xffff0000u) + __uint_as_float(u2.y & 0xffff0000u) + __uint_as_float(u3.y & 0xffff0000u);
    o.x *= 0.25f; o.y *= 0.25f; o.z *= 0.25f; o.w *= 0.25f;
    out[i] = o;
}

extern "C" void kernel_launch(void* const* d_in, const int* in_sizes, int n_in,
                              void* d_out, int out_size, void* d_ws, size_t ws_size,
                              hipStream_t stream) {
    const float* emb = (const float*)d_in[0];
    const float* sd  = (const float*)d_in[1];
    const int*   src = (const int*)d_in[2];
    const int*   dst = (const int*)d_in[3];
    float*       out = (float*)d_out;

    char* ws = (char*)d_ws;
    auto align256 = [](size_t x) { return (x + 255) & ~(size_t)255; };
    size_t off = 0;
    int*  rowptr  = (int*)(ws + off);  off += align256((size_t)N_NODES * 4);
    uint* deg     = (uint*)(ws + off); off += align256((size_t)N_NODES * 4);
    int*  bsum    = (int*)(ws + off);  off += align256((size_t)N_SCAN_BLOCKS * 4);
    uint* deg8    = (uint*)(ws + off); off += align256((size_t)N_NODES * NSUB * 4); // 4.8 MB
    uint* ranksrc = (uint*)(ws + off); off += align256((size_t)N_EDGES * 4);        // 12 MB
    int2* srcw    = (int2*)(ws + off); off += align256((size_t)N_EDGES * 8);        // 24 MB
    const size_t rowBytes = (size_t)N_NODES * EMBED_DIM * 2;                        // 19.2 MB
    uint* buf0 = (uint*)(ws + off);    off += align256(rowBytes);  // xb0, then ag3
    uint* buf1 = (uint*)(ws + off);    off += align256(rowBytes);  // ag1
    uint* buf2 = (uint*)(ws + off);                                 // ag2

    const int n4 = N_NODES * EMBED_DIM / 4;
    const int nblk4 = (n4 + 255) / 256;
    const int ublk  = (N_UNITS + 255) / 256;          // 2930
    const int nodeblk = (N_NODES + 255) / 256;        // 586

    // ---- CSR build: 8-way hist+rank -> suboff -> scan -> XCD-homed scatter ----
    hipMemsetAsync(deg8, 0, (size_t)N_NODES * NSUB * 4, stream);
    k_hist_rank<<<ublk, 256, 0, stream>>>((const int4*)dst, (const int4*)src,
                                          deg8, (uint4*)ranksrc);
    k_suboff<<<nodeblk, 256, 0, stream>>>(deg8, deg);
    k_blocksum<<<N_SCAN_BLOCKS, SCAN_BLOCK, 0, stream>>>(deg, bsum);
    k_scan_bsums<<<1, 1024, 0, stream>>>(bsum);
    k_scan_final<<<N_SCAN_BLOCKS, SCAN_BLOCK, 0, stream>>>(deg, bsum, rowptr);
    k_scatter_swz<<<2048, 256, 0, stream>>>((const int4*)dst, (const uint4*)ranksrc,
                                            sd, rowptr, deg8, srcw);

    // ---- emb -> bf16 ----
    k_to_bf16<<<nblk4, 256, 0, stream>>>((const float4*)emb, (uint2*)buf0, n4);

    // ---- 3 layers, gather-only, bf16 in/out (buf0->buf1->buf2->buf0) ----
    const int lblk = (N_NODES + 3) / 4;
    k_layer<<<lblk, 256, 0, stream>>>((const uint4*)buf0, rowptr, srcw, (uint4*)buf1);
    k_layer<<<lblk, 256, 0, stream>>>((const uint4*)buf1, rowptr, srcw, (uint4*)buf2);
    k_layer<<<lblk, 256, 0, stream>>>((const uint4*)buf2, rowptr, srcw, (uint4*)buf0);

    // ---- combine ----
    k_combine<<<nblk4, 256, 0, stream>>>((const float4*)emb, (const uint2*)buf1,
                                         (const uint2*)buf2, (const uint2*)buf0,
                                         (float4*)out, n4);
}

// Round 6
// 342.966 us; speedup vs baseline: 1.3672x; 1.3672x over previous
//
#include <hip/hip_runtime.h>

#define N_NODES   150000
#define N_EDGES   3000000
#define EMBED_DIM 64
#define N_UNITS   (N_EDGES / 4)          // 750000 int4 units
#define NREG      2344                   // regions of 64 nodes: 2344*64 = 150016
#define NCB       92                     // chunks: 92 * 8192 units = 753664 >= 750000
#define CHUNK_U   8192                   // int4-units per chunk (32768 edges)

typedef unsigned int uint;

// ---- bf16 helpers (RNE pack, shift unpack) ----
__device__ inline uint pack2_bf16(float a, float b) {
    uint ua = __float_as_uint(a);
    uint ub = __float_as_uint(b);
    ua += 0x7fffu + ((ua >> 16) & 1u);
    ub += 0x7fffu + ((ub >> 16) & 1u);
    return (ua >> 16) | (ub & 0xffff0000u);
}
#define FMA2(u, A0, A1)                                        \
    {   float _lo = __uint_as_float((u) << 16);                \
        float _hi = __uint_as_float((u) & 0xffff0000u);        \
        (A0) += w * _lo;  (A1) += w * _hi; }

// ---------- fp32 -> bf16 convert ----------
__global__ void k_to_bf16(const float4* __restrict__ in, uint2* __restrict__ out, int n4) {
    int i = blockIdx.x * blockDim.x + threadIdx.x;
    if (i < n4) {
        float4 v = in[i];
        out[i] = make_uint2(pack2_bf16(v.x, v.y), pack2_bf16(v.z, v.w));
    }
}

// ---------- 1. per-chunk region histogram (LDS counters, no global atomics) ----------
__global__ __launch_bounds__(256) void k_count(const int4* __restrict__ dst4,
                                               uint* __restrict__ bh) {
    __shared__ uint cnt[NREG];
    for (int b = threadIdx.x; b < NREG; b += 256) cnt[b] = 0;
    __syncthreads();
    int base = blockIdx.x * CHUNK_U;
    for (int i = threadIdx.x; i < CHUNK_U; i += 256) {
        int u = base + i;
        if (u < N_UNITS) {
            int4 d = dst4[u];
            atomicAdd(&cnt[d.x >> 6], 1u);
            atomicAdd(&cnt[d.y >> 6], 1u);
            atomicAdd(&cnt[d.z >> 6], 1u);
            atomicAdd(&cnt[d.w >> 6], 1u);
        }
    }
    __syncthreads();
    for (int b = threadIdx.x; b < NREG; b += 256) bh[blockIdx.x * NREG + b] = cnt[b];
}

// ---------- 2. per-bin totals (thread-per-bin, coalesced) ----------
__global__ void k_cols(const uint* __restrict__ bh, uint* __restrict__ tot) {
    int b = blockIdx.x * blockDim.x + threadIdx.x;
    if (b >= NREG) return;
    uint run = 0;
    for (int k = 0; k < NCB; ++k) run += bh[k * NREG + b];
    tot[b] = run;
}

// ---------- 3. exclusive scan of 2344 bin totals -> binPtr[0..NREG] ----------
__global__ void k_scan_small(const uint* __restrict__ tot, int* __restrict__ binPtr) {
    __shared__ uint s[1024];
    int t = threadIdx.x;
    int base = t * 3;
    uint v0 = (base + 0 < NREG) ? tot[base + 0] : 0;
    uint v1 = (base + 1 < NREG) ? tot[base + 1] : 0;
    uint v2 = (base + 2 < NREG) ? tot[base + 2] : 0;
    uint s3 = v0 + v1 + v2;
    s[t] = s3;
    __syncthreads();
    for (int off = 1; off < 1024; off <<= 1) {
        uint add = (t >= off) ? s[t - off] : 0;
        __syncthreads();
        s[t] += add;
        __syncthreads();
    }
    uint excl = s[t] - s3;
    if (base + 0 < NREG) binPtr[base + 0] = (int)excl;
    if (base + 1 < NREG) binPtr[base + 1] = (int)(excl + v0);
    if (base + 2 < NREG) binPtr[base + 2] = (int)(excl + v0 + v1);
    if (t == 1023) binPtr[NREG] = (int)s[1023];
}

// ---------- 4. turn bh counts into global write offsets ----------
__global__ void k_offsets(uint* __restrict__ bh, const int* __restrict__ binPtr) {
    int b = blockIdx.x * blockDim.x + threadIdx.x;
    if (b >= NREG) return;
    uint run = (uint)binPtr[b];
    for (int k = 0; k < NCB; ++k) {
        uint c = bh[k * NREG + b];
        bh[k * NREG + b] = run;
        run += c;
    }
}

// ---------- 5. place records into region buckets (LDS returning atomics only) ----------
// bkt[pos] = (src << 6) | (dst & 63)
__global__ __launch_bounds__(256) void k_place(const int4* __restrict__ dst4,
                                               const int4* __restrict__ src4,
                                               const uint* __restrict__ bh,
                                               uint* __restrict__ bkt) {
    __shared__ uint loff[NREG];
    for (int b = threadIdx.x; b < NREG; b += 256) loff[b] = bh[blockIdx.x * NREG + b];
    __syncthreads();
    int base = blockIdx.x * CHUNK_U;
    for (int i = threadIdx.x; i < CHUNK_U; i += 256) {
        int u = base + i;
        if (u < N_UNITS) {
            int4 d = dst4[u];
            int4 s = src4[u];
            uint p0 = atomicAdd(&loff[d.x >> 6], 1u);
            uint p1 = atomicAdd(&loff[d.y >> 6], 1u);
            uint p2 = atomicAdd(&loff[d.z >> 6], 1u);
            uint p3 = atomicAdd(&loff[d.w >> 6], 1u);
            bkt[p0] = ((uint)s.x << 6) | ((uint)d.x & 63u);
            bkt[p1] = ((uint)s.y << 6) | ((uint)d.y & 63u);
            bkt[p2] = ((uint)s.z << 6) | ((uint)d.z & 63u);
            bkt[p3] = ((uint)s.w << 6) | ((uint)d.w & 63u);
        }
    }
}

// ---------- 6. finalize CSR within each region (block per region, LDS ranks) ----------
__global__ __launch_bounds__(256) void k_finalize(const uint* __restrict__ bkt,
                                                  const int* __restrict__ binPtr,
                                                  const float* __restrict__ sd,
                                                  int* __restrict__ rowptr,
                                                  int2* __restrict__ srcw) {
    int r = blockIdx.x;
    int start = binPtr[r];
    int end   = binPtr[r + 1];
    int nbase = r * 64;
    int nloc  = N_NODES - nbase; if (nloc > 64) nloc = 64;

    __shared__ uint cnt[64];
    __shared__ uint off[64];
    if (threadIdx.x < 64) cnt[threadIdx.x] = 0;
    __syncthreads();
    for (int e = start + (int)threadIdx.x; e < end; e += 256)
        atomicAdd(&cnt[bkt[e] & 63u], 1u);
    __syncthreads();
    if (threadIdx.x == 0) {
        uint run = 0;
        for (int i = 0; i < 64; ++i) { off[i] = run; run += cnt[i]; }
    }
    __syncthreads();
    if ((int)threadIdx.x < nloc) rowptr[nbase + threadIdx.x] = start + (int)off[threadIdx.x];
    if (threadIdx.x < 64) cnt[threadIdx.x] = 0;
    __syncthreads();
    for (int e = start + (int)threadIdx.x; e < end; e += 256) {
        uint rec = bkt[e];
        uint loc = rec & 63u;
        uint s   = rec >> 6;
        uint pos = (uint)start + off[loc] + atomicAdd(&cnt[loc], 1u);
        float w = sd[s] * sd[nbase + (int)loc];
        srcw[pos] = make_int2((int)s, __float_as_int(w));
    }
}

// ---------- layer: wave-per-node gather over bf16 rows ----------
__global__ __launch_bounds__(256) void k_layer(const uint4* __restrict__ xb,
                                               const int* __restrict__ rowptr,
                                               const int2* __restrict__ srcw,
                                               uint4* __restrict__ aggb) {
    int wid = (blockIdx.x * blockDim.x + threadIdx.x) >> 6;
    if (wid >= N_NODES) return;                 // wave-uniform exit
    int lane = threadIdx.x & 63;
    int ep = lane >> 3;     // edge slot 0..7
    int j  = lane & 7;      // 16B chunk (dims j*8 .. j*8+7)

    int start = rowptr[wid];
    int end   = (wid + 1 < N_NODES) ? rowptr[wid + 1] : N_EDGES;

    float a0 = 0.f, a1 = 0.f, a2 = 0.f, a3 = 0.f;
    float a4 = 0.f, a5 = 0.f, a6 = 0.f, a7 = 0.f;
    for (int base = start; base < end; base += 8) {
        int ee = base + ep;
        if (ee < end) {
            int2 sw = srcw[ee];
            float w = __int_as_float(sw.y);
            uint4 v = xb[(size_t)sw.x * 8 + j];
            FMA2(v.x, a0, a1);
            FMA2(v.y, a2, a3);
            FMA2(v.z, a4, a5);
            FMA2(v.w, a6, a7);
        }
    }
    #pragma unroll
    for (int m = 8; m <= 32; m <<= 1) {
        a0 += __shfl_xor(a0, m, 64);
        a1 += __shfl_xor(a1, m, 64);
        a2 += __shfl_xor(a2, m, 64);
        a3 += __shfl_xor(a3, m, 64);
        a4 += __shfl_xor(a4, m, 64);
        a5 += __shfl_xor(a5, m, 64);
        a6 += __shfl_xor(a6, m, 64);
        a7 += __shfl_xor(a7, m, 64);
    }
    if (ep == 0) {
        uint4 r;
        r.x = pack2_bf16(a0, a1);
        r.y = pack2_bf16(a2, a3);
        r.z = pack2_bf16(a4, a5);
        r.w = pack2_bf16(a6, a7);
        aggb[(size_t)wid * 8 + j] = r;
    }
}

// ---------- final: out = 0.25*(emb + a1 + a2 + a3) ----------
__global__ void k_combine(const float4* __restrict__ emb,
                          const uint2* __restrict__ b1,
                          const uint2* __restrict__ b2,
                          const uint2* __restrict__ b3,
                          float4* __restrict__ out, int n4) {
    int i = blockIdx.x * blockDim.x + threadIdx.x;
    if (i >= n4) return;
    float4 e = emb[i];
    uint2 u1 = b1[i], u2 = b2[i], u3 = b3[i];
    float4 o;
    o.x = e.x + __uint_as_float(u1.x << 16)         + __uint_as_float(u2.x << 16)         + __uint_as_float(u3.x << 16);
    o.y = e.y + __uint_as_float(u1.x & 0xffff0000u) + __uint_as_float(u2.x & 0xffff0000u) + __uint_as_float(u3.x & 0xffff0000u);
    o.z = e.z + __uint_as_float(u1.y << 16)         + __uint_as_float(u2.y << 16)         + __uint_as_float(u3.y << 16);
    o.w = e.w + __uint_as_float(u1.y & 0xffff0000u) + __uint_as_float(u2.y & 0xffff0000u) + __uint_as_float(u3.y & 0xffff0000u);
    o.x *= 0.25f; o.y *= 0.25f; o.z *= 0.25f; o.w *= 0.25f;
    out[i] = o;
}

extern "C" void kernel_launch(void* const* d_in, const int* in_sizes, int n_in,
                              void* d_out, int out_size, void* d_ws, size_t ws_size,
                              hipStream_t stream) {
    const float* emb = (const float*)d_in[0];
    const float* sd  = (const float*)d_in[1];
    const int*   src = (const int*)d_in[2];
    const int*   dst = (const int*)d_in[3];
    float*       out = (float*)d_out;

    char* ws = (char*)d_ws;
    auto align256 = [](size_t x) { return (x + 255) & ~(size_t)255; };
    size_t off = 0;
    int*  rowptr = (int*)(ws + off);  off += align256((size_t)N_NODES * 4);
    uint* bh     = (uint*)(ws + off); off += align256((size_t)NCB * NREG * 4);   // 862 KB
    uint* tot    = (uint*)(ws + off); off += align256((size_t)NREG * 4);
    int*  binPtr = (int*)(ws + off);  off += align256((size_t)(NREG + 1) * 4);
    uint* bkt    = (uint*)(ws + off); off += align256((size_t)N_EDGES * 4);      // 12 MB
    int2* srcw   = (int2*)(ws + off); off += align256((size_t)N_EDGES * 8);      // 24 MB
    const size_t rowBytes = (size_t)N_NODES * EMBED_DIM * 2;                     // 19.2 MB
    uint* buf0 = (uint*)(ws + off);   off += align256(rowBytes);  // xb0, then ag3
    uint* buf1 = (uint*)(ws + off);   off += align256(rowBytes);  // ag1
    uint* buf2 = (uint*)(ws + off);                                // ag2

    const int n4 = N_NODES * EMBED_DIM / 4;
    const int nblk4 = (n4 + 255) / 256;
    const int regblk = (NREG + 255) / 256;    // 10

    // ---- CSR build: LDS-bucketed, zero global returning atomics ----
    k_count<<<NCB, 256, 0, stream>>>((const int4*)dst, bh);
    k_cols<<<regblk, 256, 0, stream>>>(bh, tot);
    k_scan_small<<<1, 1024, 0, stream>>>(tot, binPtr);
    k_offsets<<<regblk, 256, 0, stream>>>(bh, binPtr);
    k_place<<<NCB, 256, 0, stream>>>((const int4*)dst, (const int4*)src, bh, bkt);
    k_finalize<<<NREG, 256, 0, stream>>>(bkt, binPtr, sd, rowptr, srcw);

    // ---- emb -> bf16 ----
    k_to_bf16<<<nblk4, 256, 0, stream>>>((const float4*)emb, (uint2*)buf0, n4);

    // ---- 3 layers, gather-only, bf16 in/out (buf0->buf1->buf2->buf0) ----
    const int lblk = (N_NODES + 3) / 4;
    k_layer<<<lblk, 256, 0, stream>>>((const uint4*)buf0, rowptr, srcw, (uint4*)buf1);
    k_layer<<<lblk, 256, 0, stream>>>((const uint4*)buf1, rowptr, srcw, (uint4*)buf2);
    k_layer<<<lblk, 256, 0, stream>>>((const uint4*)buf2, rowptr, srcw, (uint4*)buf0);

    // ---- combine ----
    k_combine<<<nblk4, 256, 0, stream>>>((const float4*)emb, (const uint2*)buf1,
                                         (const uint2*)buf2, (const uint2*)buf0,
                                         (float4*)out, n4);
}